// Round 3
// baseline (968.171 us; speedup 1.0000x reference)
//
#include <hip/hip_runtime.h>
#include <math.h>

#define NQ   1024
#define KD   128
#define CAP  131072
#define VD   256
#define TOPK 5
#define EPSF 1e-8f

#define M_TILE  128   // queries per block
#define N_SUB   128   // keys per sub-tile
#define K_SLICE 32    // K staged per B slice

__device__ __forceinline__ bool kbetter(float sa, int ia, float sb, int ib) {
  // descending score, tie -> lower index (matches lax.top_k)
  return (sa > sb) || (sa == sb && ia < ib);
}

__device__ __forceinline__ void insert5(float (&t)[5], int (&ix)[5], float s, int idx) {
  if (kbetter(s, idx, t[4], ix[4])) {
    t[4] = s; ix[4] = idx;
#pragma unroll
    for (int j = 4; j >= 1; --j) {
      if (kbetter(t[j], ix[j], t[j-1], ix[j-1])) {
        float tf = t[j]; t[j] = t[j-1]; t[j-1] = tf;
        int tii = ix[j]; ix[j] = ix[j-1]; ix[j-1] = tii;
      }
    }
  }
}

// ---------------- K1: query row norms ----------------
__global__ void k_qnorm(const float* __restrict__ q, float* __restrict__ nrm_q) {
  int m = blockIdx.x;
  int d = threadIdx.x;  // 128
  float v = q[m * KD + d];
  float ss = v * v;
#pragma unroll
  for (int mk = 1; mk <= 32; mk <<= 1) ss += __shfl_xor(ss, mk, 64);
  __shared__ float red[2];
  if ((d & 63) == 0) red[d >> 6] = ss;
  __syncthreads();
  if (d == 0) nrm_q[m] = fmaxf(sqrtf(red[0] + red[1]), EPSF);
}

// ---------------- K2: key row norms ----------------
__global__ void k_knorm(const float* __restrict__ keys, float* __restrict__ nrm_k) {
  int t = threadIdx.x;                      // 256 -> 64 rows/block
  int row = blockIdx.x * 64 + (t >> 2);
  const float* kr = keys + (size_t)row * KD + (t & 3) * 32;
  float ss = 0.f;
#pragma unroll
  for (int i = 0; i < 8; ++i) {
    float4 x = *(const float4*)(kr + i * 4);
    ss += x.x * x.x + x.y * x.y + x.z * x.z + x.w * x.w;
  }
  ss += __shfl_xor(ss, 1, 64);
  ss += __shfl_xor(ss, 2, 64);
  if ((t & 3) == 0) nrm_k[row] = fmaxf(sqrtf(ss), EPSF);
}

// ---------------- K3: fused scores + per-chunk top-5 ----------------
#define FMA4(d, a, b) \
  d.x = fmaf(a, b.x, d.x); d.y = fmaf(a, b.y, d.y); \
  d.z = fmaf(a, b.z, d.z); d.w = fmaf(a, b.w, d.w)

template <int NCHUNK>
__global__ __launch_bounds__(256, 2)
void k_scores(const float* __restrict__ q, const float* __restrict__ keys,
              const float* __restrict__ nrm_q, const float* __restrict__ nrm_k,
              float* __restrict__ cand_s, int* __restrict__ cand_i) {
  constexpr int CHUNK_N = CAP / NCHUNK;
  __shared__ __align__(16) float A[2 * K_SLICE * M_TILE];  // [64 k][128 m], 32 KB
  __shared__ __align__(16) float Bs[K_SLICE * N_SUB];      // [32 k][128 n], 16 KB

  const int tid = threadIdx.x;
  const int tx = tid & 15, ty = tid >> 4;
  const int chunk = blockIdx.x;          // 0..NCHUNK-1
  const int m0 = blockIdx.y * M_TILE;    // 0..7 tiles
  const int n0 = chunk * CHUNK_N;

  const int srow = tid & 127;            // staging row (m-local or n-local)
  const int shalf = tid >> 7;            // 0..1

  const float qn = nrm_q[m0 + srow];
  const float* qrow = q + (size_t)(m0 + srow) * KD;

  float tm[2][4][5]; int ti[2][4][5];
#pragma unroll
  for (int h = 0; h < 2; ++h)
#pragma unroll
    for (int r = 0; r < 4; ++r)
#pragma unroll
      for (int p = 0; p < 5; ++p) { tm[h][r][p] = -__builtin_inff(); ti[h][r][p] = 0x7fffffff; }

  for (int ns = 0; ns < CHUNK_N / N_SUB; ++ns) {
    const int nb = n0 + ns * N_SUB;
    const float kn = nrm_k[nb + srow];
    const float* krow = keys + (size_t)(nb + srow) * KD;

    float4 acc[2][4][2];
#pragma unroll
    for (int h = 0; h < 2; ++h)
#pragma unroll
      for (int r = 0; r < 4; ++r)
#pragma unroll
        for (int g = 0; g < 2; ++g) acc[h][r][g] = make_float4(0.f, 0.f, 0.f, 0.f);

    for (int s = 0; s < 4; ++s) {
      __syncthreads();  // prior compute done before overwriting LDS
      if ((s & 1) == 0) {
        // stage A half: global k in [(s>>1)*64, +64), layout A[k_local][m]
#pragma unroll
        for (int it = 0; it < 8; ++it) {
          int ql = shalf + it * 2;              // 0..15
          int kg = (s >> 1) * 64 + ql * 4;
          float4 v = *(const float4*)(qrow + kg);
          A[(ql * 4 + 0) * M_TILE + srow] = v.x / qn;
          A[(ql * 4 + 1) * M_TILE + srow] = v.y / qn;
          A[(ql * 4 + 2) * M_TILE + srow] = v.z / qn;
          A[(ql * 4 + 3) * M_TILE + srow] = v.w / qn;
        }
      }
      // stage B slice: global k in [s*32, +32), layout Bs[k_local][n]
#pragma unroll
      for (int it = 0; it < 4; ++it) {
        int ql = shalf + it * 2;                // 0..7
        float4 v = *(const float4*)(krow + s * K_SLICE + ql * 4);
        Bs[(ql * 4 + 0) * N_SUB + srow] = v.x / kn;
        Bs[(ql * 4 + 1) * N_SUB + srow] = v.y / kn;
        Bs[(ql * 4 + 2) * N_SUB + srow] = v.z / kn;
        Bs[(ql * 4 + 3) * N_SUB + srow] = v.w / kn;
      }
      __syncthreads();

      const float* Abase = &A[(s & 1) * K_SLICE * M_TILE];
#pragma unroll 4
      for (int k = 0; k < K_SLICE; ++k) {
        const float* Ak = Abase + k * M_TILE;
        const float* Bk = &Bs[k * N_SUB];
        float4 a0 = *(const float4*)(Ak + (ty << 2));        // m = m0+ty*4+r
        float4 a1 = *(const float4*)(Ak + (ty << 2) + 64);   // +64
        float4 b0 = *(const float4*)(Bk + (tx << 2));        // n = nb+tx*4+c
        float4 b1 = *(const float4*)(Bk + (tx << 2) + 64);   // +64
        FMA4(acc[0][0][0], a0.x, b0); FMA4(acc[0][0][1], a0.x, b1);
        FMA4(acc[0][1][0], a0.y, b0); FMA4(acc[0][1][1], a0.y, b1);
        FMA4(acc[0][2][0], a0.z, b0); FMA4(acc[0][2][1], a0.z, b1);
        FMA4(acc[0][3][0], a0.w, b0); FMA4(acc[0][3][1], a0.w, b1);
        FMA4(acc[1][0][0], a1.x, b0); FMA4(acc[1][0][1], a1.x, b1);
        FMA4(acc[1][1][0], a1.y, b0); FMA4(acc[1][1][1], a1.y, b1);
        FMA4(acc[1][2][0], a1.z, b0); FMA4(acc[1][2][1], a1.z, b1);
        FMA4(acc[1][3][0], a1.w, b0); FMA4(acc[1][3][1], a1.w, b1);
      }
    }

    // insert this sub-tile's scores into per-thread running top5
#pragma unroll
    for (int h = 0; h < 2; ++h)
#pragma unroll
      for (int r = 0; r < 4; ++r)
#pragma unroll
        for (int g = 0; g < 2; ++g) {
          float4 v = acc[h][r][g];
          int base = nb + g * 64 + (tx << 2);
          insert5(tm[h][r], ti[h][r], v.x, base + 0);
          insert5(tm[h][r], ti[h][r], v.y, base + 1);
          insert5(tm[h][r], ti[h][r], v.z, base + 2);
          insert5(tm[h][r], ti[h][r], v.w, base + 3);
        }
  }

  // butterfly merge over the 16 tx lanes (same ty -> same m rows), write chunk top5
#pragma unroll
  for (int h = 0; h < 2; ++h)
#pragma unroll
    for (int r = 0; r < 4; ++r) {
      float v[5]; int j[5];
#pragma unroll
      for (int p = 0; p < 5; ++p) { v[p] = tm[h][r][p]; j[p] = ti[h][r][p]; }
#pragma unroll
      for (int mk = 1; mk <= 8; mk <<= 1) {
        float ov[5]; int oj[5];
#pragma unroll
        for (int p = 0; p < 5; ++p) {
          ov[p] = __shfl_xor(v[p], mk, 64);
          oj[p] = __shfl_xor(j[p], mk, 64);
        }
#pragma unroll
        for (int p = 0; p < 5; ++p) insert5(v, j, ov[p], oj[p]);
      }
      if (tx == 0) {
        int m = m0 + (ty << 2) + r + h * 64;
        size_t off = ((size_t)m * NCHUNK + chunk) * TOPK;
#pragma unroll
        for (int p = 0; p < 5; ++p) { cand_s[off + p] = v[p]; cand_i[off + p] = j[p]; }
      }
    }
}

// ---------------- K4: merge chunk candidates, gather values, mean ----------------
template <int NCHUNK>
__global__ void k_fuse(const float* __restrict__ cand_s, const int* __restrict__ cand_i,
                       const float* __restrict__ values, float* __restrict__ out) {
  constexpr int NCAND = NCHUNK * TOPK;
  int m = blockIdx.x;
  int lane = threadIdx.x;  // 64
  const float* cs = cand_s + (size_t)m * NCAND;
  const int* ci = cand_i + (size_t)m * NCAND;
  float v[5]; int j[5];
#pragma unroll
  for (int p = 0; p < 5; ++p) { v[p] = -__builtin_inff(); j[p] = 0x7fffffff; }
#pragma unroll
  for (int t = 0; t < (NCAND + 63) / 64; ++t) {
    int c = lane + t * 64;
    if (c < NCAND) insert5(v, j, cs[c], ci[c]);
  }
#pragma unroll
  for (int mk = 1; mk <= 32; mk <<= 1) {
    float ov[5]; int oj[5];
#pragma unroll
    for (int p = 0; p < 5; ++p) { ov[p] = __shfl_xor(v[p], mk, 64); oj[p] = __shfl_xor(j[p], mk, 64); }
#pragma unroll
    for (int p = 0; p < 5; ++p) insert5(v, j, ov[p], oj[p]);
  }
  float4 sum = make_float4(0.f, 0.f, 0.f, 0.f);
#pragma unroll
  for (int p = 0; p < 5; ++p) {
    int idx = __shfl(j[p], 0, 64);
    const float4 t4 = *(const float4*)(values + (size_t)idx * VD + (lane << 2));
    sum.x += t4.x; sum.y += t4.y; sum.z += t4.z; sum.w += t4.w;
  }
  float4 o = make_float4(sum.x * 0.2f, sum.y * 0.2f, sum.z * 0.2f, sum.w * 0.2f);
  *(float4*)(out + (size_t)m * VD + (lane << 2)) = o;
}

template <int NCHUNK>
static void launch_all(const float* q, const float* keys, const float* values,
                       float* out, void* d_ws, hipStream_t stream) {
  float* nrm_q  = (float*)d_ws;                               // 1024
  float* nrm_k  = nrm_q + NQ;                                 // 131072
  float* cand_s = nrm_k + CAP;                                // NQ*NCHUNK*5
  int*   cand_i = (int*)(cand_s + (size_t)NQ * NCHUNK * TOPK);

  k_qnorm<<<NQ, KD, 0, stream>>>(q, nrm_q);
  k_knorm<<<CAP / 64, 256, 0, stream>>>(keys, nrm_k);
  k_scores<NCHUNK><<<dim3(NCHUNK, NQ / M_TILE), 256, 0, stream>>>(q, keys, nrm_q, nrm_k, cand_s, cand_i);
  k_fuse<NCHUNK><<<NQ, 64, 0, stream>>>(cand_s, cand_i, values, out);
}

extern "C" void kernel_launch(void* const* d_in, const int* in_sizes, int n_in,
                              void* d_out, int out_size, void* d_ws, size_t ws_size,
                              hipStream_t stream) {
  const float* q      = (const float*)d_in[0];
  const float* keys   = (const float*)d_in[1];
  const float* values = (const float*)d_in[2];
  // d_in[3] = topk (==5, hardcoded)
  float* out = (float*)d_out;

  // ws footprint for a given chunk count: norms + cand_s(float) + cand_i(int)
  auto need = [](int nch) -> size_t {
    return (size_t)(NQ + CAP) * 4 + (size_t)NQ * nch * TOPK * 8;
  };

  if (ws_size >= need(128))      launch_all<128>(q, keys, values, out, d_ws, stream);
  else if (ws_size >= need(64))  launch_all<64>(q, keys, values, out, d_ws, stream);
  else if (ws_size >= need(16))  launch_all<16>(q, keys, values, out, d_ws, stream);
  else                           launch_all<4>(q, keys, values, out, d_ws, stream);
}

// Round 4
// 624.167 us; speedup vs baseline: 1.5511x; 1.5511x over previous
//
#include <hip/hip_runtime.h>
#include <math.h>

#define NQ   1024
#define KD   128
#define CAP  131072
#define VD   256
#define TOPK 5
#define EPSF 1e-8f

#define KT 128           // keys per LDS tile

typedef _Float16 half8 __attribute__((ext_vector_type(8)));
typedef float f32x4 __attribute__((ext_vector_type(4)));

__device__ __forceinline__ bool kbetter(float sa, int ia, float sb, int ib) {
  // descending score, tie -> lower index (matches lax.top_k)
  return (sa > sb) || (sa == sb && ia < ib);
}

__device__ __forceinline__ void insert5(float (&t)[5], int (&ix)[5], float s, int idx) {
  if (kbetter(s, idx, t[4], ix[4])) {
    t[4] = s; ix[4] = idx;
#pragma unroll
    for (int j = 4; j >= 1; --j) {
      if (kbetter(t[j], ix[j], t[j-1], ix[j-1])) {
        float tf = t[j]; t[j] = t[j-1]; t[j-1] = tf;
        int tii = ix[j]; ix[j] = ix[j-1]; ix[j-1] = tii;
      }
    }
  }
}

// ---------------- K1: query prep — normalize + fp16 hi/lo split ----------------
__global__ void k_qprep(const float* __restrict__ q,
                        _Float16* __restrict__ qhi, _Float16* __restrict__ qlo) {
  int m = blockIdx.x;
  int d = threadIdx.x;  // 128
  float v = q[m * KD + d];
  float ss = v * v;
#pragma unroll
  for (int mk = 1; mk <= 32; mk <<= 1) ss += __shfl_xor(ss, mk, 64);
  __shared__ float red[2];
  if ((d & 63) == 0) red[d >> 6] = ss;
  __syncthreads();
  float n = fmaxf(sqrtf(red[0] + red[1]), EPSF);
  float xn = v / n;                       // same op order as reference
  _Float16 hi = (_Float16)xn;
  _Float16 lo = (_Float16)(xn - (float)hi);
  qhi[m * KD + d] = hi;
  qlo[m * KD + d] = lo;
}

// ---------------- K2: key inverse norms ----------------
__global__ void k_knorm(const float* __restrict__ keys, float* __restrict__ inv_nk) {
  int t = threadIdx.x;                      // 256 -> 64 rows/block
  int row = blockIdx.x * 64 + (t >> 2);
  const float* kr = keys + (size_t)row * KD + (t & 3) * 32;
  float ss = 0.f;
#pragma unroll
  for (int i = 0; i < 8; ++i) {
    float4 x = *(const float4*)(kr + i * 4);
    ss += x.x * x.x + x.y * x.y + x.z * x.z + x.w * x.w;
  }
  ss += __shfl_xor(ss, 1, 64);
  ss += __shfl_xor(ss, 2, 64);
  if ((t & 3) == 0) inv_nk[row] = 1.0f / fmaxf(sqrtf(ss), EPSF);
}

// ---------------- K3: MFMA scores (fp16 hi/lo split) + per-chunk top-5 ----------------
// Block: 512 threads = 8 waves. Wave w owns 16 queries. Keys staged 128/tile in LDS.
// MFMA f32_16x16x32_f16 D-layout: score[q=(lane>>4)*4+reg][key=lane&15].
template <int NCHUNK>
__global__ __launch_bounds__(512, 2)
void k_scores(const float* __restrict__ keys,
              const _Float16* __restrict__ qhi, const _Float16* __restrict__ qlo,
              const float* __restrict__ inv_nk,
              float* __restrict__ cand_s, int* __restrict__ cand_i) {
  constexpr int CHUNK_N = CAP / NCHUNK;
  constexpr int NT = CHUNK_N / KT;
  __shared__ __align__(16) _Float16 KH[KT * KD];  // 32 KB, XOR-swizzled rows
  __shared__ __align__(16) _Float16 KL[KT * KD];  // 32 KB

  const int tid = threadIdx.x;
  const int l = tid & 63;
  const int w = tid >> 6;            // wave 0..7
  const int col = l & 15;            // key within 16-tile
  const int kg = l >> 4;             // k-group 0..3
  const int chunk = blockIdx.x;
  const int m0 = blockIdx.y * 128;
  const int n0 = chunk * CHUNK_N;

  // staging role: row r (key within tile), k-quarter kq
  const int sr = tid >> 2;           // 0..127
  const int skq = tid & 3;           // 0..3

  // Q fragments in registers: rows m0 + w*16 + col, k = ks*32 + kg*8 + j
  half8 qh[4], ql[4];
  {
    const size_t qoff = (size_t)(m0 + w * 16 + col) * KD + kg * 8;
#pragma unroll
    for (int ks = 0; ks < 4; ++ks) {
      qh[ks] = *(const half8*)(qhi + qoff + ks * 32);
      ql[ks] = *(const half8*)(qlo + qoff + ks * 32);
    }
  }

  float tm[4][5]; int ti[4][5];
#pragma unroll
  for (int p = 0; p < 4; ++p)
#pragma unroll
    for (int s = 0; s < 5; ++s) { tm[p][s] = -__builtin_inff(); ti[p][s] = 0x7fffffff; }

  // ---- staging helpers (inline) ----
  float4 g[8];
  float ginv;
  // prologue: load tile 0
  {
    const float* src = keys + (size_t)(n0 + sr) * KD + skq * 32;
#pragma unroll
    for (int i = 0; i < 8; ++i) g[i] = *(const float4*)(src + i * 4);
    ginv = inv_nk[n0 + sr];
  }
  // convert + write tile 0
  {
#pragma unroll
    for (int i = 0; i < 4; ++i) {
      float4 a = g[2 * i], b = g[2 * i + 1];
      float x0 = a.x * ginv, x1 = a.y * ginv, x2 = a.z * ginv, x3 = a.w * ginv;
      float x4 = b.x * ginv, x5 = b.y * ginv, x6 = b.z * ginv, x7 = b.w * ginv;
      half8 h, lo8;
      h[0] = (_Float16)x0; lo8[0] = (_Float16)(x0 - (float)h[0]);
      h[1] = (_Float16)x1; lo8[1] = (_Float16)(x1 - (float)h[1]);
      h[2] = (_Float16)x2; lo8[2] = (_Float16)(x2 - (float)h[2]);
      h[3] = (_Float16)x3; lo8[3] = (_Float16)(x3 - (float)h[3]);
      h[4] = (_Float16)x4; lo8[4] = (_Float16)(x4 - (float)h[4]);
      h[5] = (_Float16)x5; lo8[5] = (_Float16)(x5 - (float)h[5]);
      h[6] = (_Float16)x6; lo8[6] = (_Float16)(x6 - (float)h[6]);
      h[7] = (_Float16)x7; lo8[7] = (_Float16)(x7 - (float)h[7]);
      int e = (sr * KD + skq * 32 + i * 8) ^ ((sr & 7) << 3);
      *(half8*)&KH[e] = h;
      *(half8*)&KL[e] = lo8;
    }
  }
  __syncthreads();

  for (int t = 0; t < NT; ++t) {
    // issue next tile's global loads early (latency hides under compute)
    if (t + 1 < NT) {
      const float* src = keys + (size_t)(n0 + (t + 1) * KT + sr) * KD + skq * 32;
#pragma unroll
      for (int i = 0; i < 8; ++i) g[i] = *(const float4*)(src + i * 4);
      ginv = inv_nk[n0 + (t + 1) * KT + sr];
    }

    // ---- compute current tile: 8 col-tiles of 16 keys, paired for ILP ----
    const int kb0 = n0 + t * KT;
#pragma unroll
    for (int ct = 0; ct < 8; ct += 2) {
      f32x4 acc0 = {0.f, 0.f, 0.f, 0.f};
      f32x4 acc1 = {0.f, 0.f, 0.f, 0.f};
      const int kr0 = ct * 16 + col;
      const int kr1 = kr0 + 16;
      const int sw0 = (kr0 & 7) << 3;
      const int sw1 = (kr1 & 7) << 3;
#pragma unroll
      for (int ks = 0; ks < 4; ++ks) {
        int e0 = (kr0 * KD + ks * 32 + kg * 8) ^ sw0;
        int e1 = (kr1 * KD + ks * 32 + kg * 8) ^ sw1;
        half8 bh0 = *(const half8*)&KH[e0];
        half8 bl0 = *(const half8*)&KL[e0];
        half8 bh1 = *(const half8*)&KH[e1];
        half8 bl1 = *(const half8*)&KL[e1];
        acc0 = __builtin_amdgcn_mfma_f32_16x16x32_f16(qh[ks], bh0, acc0, 0, 0, 0);
        acc1 = __builtin_amdgcn_mfma_f32_16x16x32_f16(qh[ks], bh1, acc1, 0, 0, 0);
        acc0 = __builtin_amdgcn_mfma_f32_16x16x32_f16(ql[ks], bh0, acc0, 0, 0, 0);
        acc1 = __builtin_amdgcn_mfma_f32_16x16x32_f16(ql[ks], bh1, acc1, 0, 0, 0);
        acc0 = __builtin_amdgcn_mfma_f32_16x16x32_f16(qh[ks], bl0, acc0, 0, 0, 0);
        acc1 = __builtin_amdgcn_mfma_f32_16x16x32_f16(qh[ks], bl1, acc1, 0, 0, 0);
      }
      const int ki0 = kb0 + kr0;
      const int ki1 = kb0 + kr1;
#pragma unroll
      for (int p = 0; p < 4; ++p) {
        insert5(tm[p], ti[p], acc0[p], ki0);
        insert5(tm[p], ti[p], acc1[p], ki1);
      }
    }
    __syncthreads();   // all waves done reading KH/KL

    if (t + 1 < NT) {
      // convert + write next tile
#pragma unroll
      for (int i = 0; i < 4; ++i) {
        float4 a = g[2 * i], b = g[2 * i + 1];
        float x0 = a.x * ginv, x1 = a.y * ginv, x2 = a.z * ginv, x3 = a.w * ginv;
        float x4 = b.x * ginv, x5 = b.y * ginv, x6 = b.z * ginv, x7 = b.w * ginv;
        half8 h, lo8;
        h[0] = (_Float16)x0; lo8[0] = (_Float16)(x0 - (float)h[0]);
        h[1] = (_Float16)x1; lo8[1] = (_Float16)(x1 - (float)h[1]);
        h[2] = (_Float16)x2; lo8[2] = (_Float16)(x2 - (float)h[2]);
        h[3] = (_Float16)x3; lo8[3] = (_Float16)(x3 - (float)h[3]);
        h[4] = (_Float16)x4; lo8[4] = (_Float16)(x4 - (float)h[4]);
        h[5] = (_Float16)x5; lo8[5] = (_Float16)(x5 - (float)h[5]);
        h[6] = (_Float16)x6; lo8[6] = (_Float16)(x6 - (float)h[6]);
        h[7] = (_Float16)x7; lo8[7] = (_Float16)(x7 - (float)h[7]);
        int e = (sr * KD + skq * 32 + i * 8) ^ ((sr & 7) << 3);
        *(half8*)&KH[e] = h;
        *(half8*)&KL[e] = lo8;
      }
      __syncthreads();
    }
  }

  // ---- butterfly merge over 16 lanes sharing a query group (same kg) ----
#pragma unroll
  for (int p = 0; p < 4; ++p) {
    float v[5]; int jx[5];
#pragma unroll
    for (int s = 0; s < 5; ++s) { v[s] = tm[p][s]; jx[s] = ti[p][s]; }
#pragma unroll
    for (int mk = 1; mk <= 8; mk <<= 1) {
      float ov[5]; int oj[5];
#pragma unroll
      for (int s = 0; s < 5; ++s) {
        ov[s] = __shfl_xor(v[s], mk, 64);
        oj[s] = __shfl_xor(jx[s], mk, 64);
      }
#pragma unroll
      for (int s = 0; s < 5; ++s) insert5(v, jx, ov[s], oj[s]);
    }
    if (col == 0) {
      int m = m0 + w * 16 + kg * 4 + p;
      size_t off = ((size_t)m * NCHUNK + chunk) * TOPK;
#pragma unroll
      for (int s = 0; s < 5; ++s) { cand_s[off + s] = v[s]; cand_i[off + s] = jx[s]; }
    }
  }
}

// ---------------- K4: merge chunk candidates, gather values, mean ----------------
template <int NCHUNK>
__global__ void k_fuse(const float* __restrict__ cand_s, const int* __restrict__ cand_i,
                       const float* __restrict__ values, float* __restrict__ out) {
  constexpr int NCAND = NCHUNK * TOPK;
  int m = blockIdx.x;
  int lane = threadIdx.x;  // 64
  const float* cs = cand_s + (size_t)m * NCAND;
  const int* ci = cand_i + (size_t)m * NCAND;
  float v[5]; int j[5];
#pragma unroll
  for (int p = 0; p < 5; ++p) { v[p] = -__builtin_inff(); j[p] = 0x7fffffff; }
#pragma unroll
  for (int t = 0; t < (NCAND + 63) / 64; ++t) {
    int c = lane + t * 64;
    if (c < NCAND) insert5(v, j, cs[c], ci[c]);
  }
#pragma unroll
  for (int mk = 1; mk <= 32; mk <<= 1) {
    float ov[5]; int oj[5];
#pragma unroll
    for (int p = 0; p < 5; ++p) { ov[p] = __shfl_xor(v[p], mk, 64); oj[p] = __shfl_xor(j[p], mk, 64); }
#pragma unroll
    for (int p = 0; p < 5; ++p) insert5(v, j, ov[p], oj[p]);
  }
  float4 sum = make_float4(0.f, 0.f, 0.f, 0.f);
#pragma unroll
  for (int p = 0; p < 5; ++p) {
    int idx = __shfl(j[p], 0, 64);
    const float4 t4 = *(const float4*)(values + (size_t)idx * VD + (lane << 2));
    sum.x += t4.x; sum.y += t4.y; sum.z += t4.z; sum.w += t4.w;
  }
  float4 o = make_float4(sum.x * 0.2f, sum.y * 0.2f, sum.z * 0.2f, sum.w * 0.2f);
  *(float4*)(out + (size_t)m * VD + (lane << 2)) = o;
}

template <int NCHUNK>
static void launch_all(const float* q, const float* keys, const float* values,
                       float* out, void* d_ws, hipStream_t stream) {
  _Float16* qhi  = (_Float16*)d_ws;                 // 1024*128 f16 = 256 KB
  _Float16* qlo  = qhi + (size_t)NQ * KD;           // 256 KB
  float* inv_nk  = (float*)(qlo + (size_t)NQ * KD); // 512 KB
  float* cand_s  = inv_nk + CAP;
  int*   cand_i  = (int*)(cand_s + (size_t)NQ * NCHUNK * TOPK);

  k_qprep<<<NQ, KD, 0, stream>>>(q, qhi, qlo);
  k_knorm<<<CAP / 64, 256, 0, stream>>>(keys, inv_nk);
  k_scores<NCHUNK><<<dim3(NCHUNK, NQ / 128), 512, 0, stream>>>(keys, qhi, qlo, inv_nk, cand_s, cand_i);
  k_fuse<NCHUNK><<<NQ, 64, 0, stream>>>(cand_s, cand_i, values, out);
}

extern "C" void kernel_launch(void* const* d_in, const int* in_sizes, int n_in,
                              void* d_out, int out_size, void* d_ws, size_t ws_size,
                              hipStream_t stream) {
  const float* q      = (const float*)d_in[0];
  const float* keys   = (const float*)d_in[1];
  const float* values = (const float*)d_in[2];
  // d_in[3] = topk (==5, hardcoded)
  float* out = (float*)d_out;

  // ws footprint: qhi+qlo (512KB) + inv_nk (512KB) + cand_s/cand_i
  auto need = [](int nch) -> size_t {
    return (size_t)NQ * KD * 4 + (size_t)CAP * 4 + (size_t)NQ * nch * TOPK * 8;
  };

  if (ws_size >= need(128))      launch_all<128>(q, keys, values, out, d_ws, stream);
  else if (ws_size >= need(64))  launch_all<64>(q, keys, values, out, d_ws, stream);
  else if (ws_size >= need(16))  launch_all<16>(q, keys, values, out, d_ws, stream);
  else                           launch_all<4>(q, keys, values, out, d_ws, stream);
}